// Round 1
// baseline (11410.417 us; speedup 1.0000x reference)
//
#include <hip/hip_runtime.h>

typedef _Float16 f16;
typedef _Float16 half8 __attribute__((ext_vector_type(8)));
typedef _Float16 half4_t __attribute__((ext_vector_type(4)));
typedef float floatx4 __attribute__((ext_vector_type(4)));

#define BB 64
#define TT 512
#define II 2048
#define HH 256
#define GG 768  // 3*H

__device__ inline float sigm(float x) { return 1.0f / (1.0f + __expf(-x)); }
__device__ inline float tanh_(float x) { float t = __expf(2.0f * x); return 1.0f - 2.0f / (t + 1.0f); }

// ---------------- zero fill (16B granules) ----------------
__global__ void zero16(uint4* p, int n16) {
    int i = blockIdx.x * blockDim.x + threadIdx.x;
    if (i < n16) p[i] = make_uint4(0u, 0u, 0u, 0u);
}

// ---------------- fp32 -> fp16 convert ----------------
__global__ void cvt(const float* __restrict__ s, f16* __restrict__ d, int n) {
    int i = (blockIdx.x * blockDim.x + threadIdx.x) * 4;
    if (i + 3 < n) {
        float4 v = *(const float4*)(s + i);
        d[i + 0] = (f16)v.x; d[i + 1] = (f16)v.y; d[i + 2] = (f16)v.z; d[i + 3] = (f16)v.w;
    } else {
        for (; i < n; ++i) d[i] = (f16)s[i];
    }
}

// ---------------- input projection GEMM ----------------
// out[M=32768][768] = A[M][K] @ W[768][K]^T + bias[768]
// REMAP: A is x (fp32, [b][t][I] layout, row r=(t,b) -> x[b][t][:]), convert in-tile.
// else:  A is fp16 rows contiguous with stride K.
template <int K, bool REMAP>
__global__ __launch_bounds__(256) void proj(const void* __restrict__ Avoid,
                                            const f16* __restrict__ W,
                                            const float* __restrict__ bias,
                                            float* __restrict__ out) {
    __shared__ f16 As[128][40];  // 128 x 32 (+8 pad): 16B-aligned rows
    __shared__ f16 Bs[128][40];
    const int tid = threadIdx.x;
    const int wave = tid >> 6, lane = tid & 63, quad = lane >> 4, col = lane & 15;
    const int nt = blockIdx.x, mt = blockIdx.y;
    const int wm = wave >> 1, wn = wave & 1;

    floatx4 acc[4][4];
    const floatx4 z4 = {0.0f, 0.0f, 0.0f, 0.0f};
    for (int a = 0; a < 4; ++a)
        for (int b = 0; b < 4; ++b) acc[a][b] = z4;

    const int srow = tid >> 1;   // staging: 2 threads per row
    const int kh = tid & 1;      // k-half (16 elements each)

    for (int kt = 0; kt < K / 32; ++kt) {
        const int k0 = kt * 32;
        __syncthreads();
        if (REMAP) {
            const float* x = (const float*)Avoid;
            int r = mt * 128 + srow;
            int t = r >> 6, b = r & 63;
            const float* src = x + ((size_t)b * TT + t) * (size_t)II + k0 + kh * 16;
            for (int j = 0; j < 4; ++j) {
                float4 v = *(const float4*)(src + j * 4);
                half4_t h;
                h.x = (f16)v.x; h.y = (f16)v.y; h.z = (f16)v.z; h.w = (f16)v.w;
                *(half4_t*)&As[srow][kh * 16 + j * 4] = h;
            }
        } else {
            const f16* Af = (const f16*)Avoid;
            int r = mt * 128 + srow;
            const f16* src = Af + (size_t)r * K + k0 + kh * 16;
            uint4* dst = (uint4*)&As[srow][kh * 16];
            dst[0] = *(const uint4*)(src);
            dst[1] = *(const uint4*)(src + 8);
        }
        {
            const f16* src = W + (size_t)(nt * 128 + srow) * K + k0 + kh * 16;
            uint4* dst = (uint4*)&Bs[srow][kh * 16];
            dst[0] = *(const uint4*)(src);
            dst[1] = *(const uint4*)(src + 8);
        }
        __syncthreads();

        half8 af[4], bf[4];
        for (int mi = 0; mi < 4; ++mi) af[mi] = *(const half8*)&As[wm * 64 + mi * 16 + col][quad * 8];
        for (int ni = 0; ni < 4; ++ni) bf[ni] = *(const half8*)&Bs[wn * 64 + ni * 16 + col][quad * 8];
        for (int mi = 0; mi < 4; ++mi)
            for (int ni = 0; ni < 4; ++ni)
                acc[mi][ni] = __builtin_amdgcn_mfma_f32_16x16x32_f16(af[mi], bf[ni], acc[mi][ni], 0, 0, 0);
    }

    for (int mi = 0; mi < 4; ++mi)
        for (int ni = 0; ni < 4; ++ni)
            for (int r2 = 0; r2 < 4; ++r2) {
                int m = mt * 128 + wm * 64 + mi * 16 + quad * 4 + r2;
                int n = nt * 128 + wn * 64 + ni * 16 + col;
                out[(size_t)m * GG + n] = acc[mi][ni][r2] + bias[n];
            }
}

// ---------------- one GRU timestep ----------------
// grid = 8 WGs; WG owns 32 channels (c0..c0+31) => 96 w_hh rows {r,z,n} staged in LDS.
// A = h(t-1) fp16 from hs_ext[t], loaded directly into fragments from global.
// State carried fp32 in h32 ping-pong; fp16 copy -> hs_ext[t+1].
__global__ __launch_bounds__(256) void gru_step(const float* __restrict__ xg,
                                                const f16* __restrict__ whh,
                                                const float* __restrict__ bhh,
                                                f16* __restrict__ hs_ext,
                                                float* __restrict__ h32, int t) {
    __shared__ f16 Bs[96][264];  // 96 x 256 (+8 pad)
    const int tid = threadIdx.x, wave = tid >> 6, lane = tid & 63, quad = lane >> 4, col = lane & 15;
    const int c0 = blockIdx.x * 32;

    // stage w_hh slice: Bs rows [0,32)=r, [32,64)=z, [64,96)=n
    for (int v = tid; v < 96 * 32; v += 256) {
        int rr = v >> 5, ch = v & 31;
        int g = rr >> 5, cloc = rr & 31;
        *(uint4*)&Bs[rr][ch * 8] =
            *(const uint4*)(whh + ((size_t)(g * 256 + c0 + cloc)) * 256 + ch * 8);
    }

    // A fragments: full K=256 for this wave's 16 batch rows
    const f16* hA = hs_ext + (size_t)t * (BB * HH);
    const int m = wave * 16 + col;
    half8 af[8];
    for (int kt = 0; kt < 8; ++kt)
        af[kt] = *(const half8*)(hA + (size_t)m * 256 + kt * 32 + quad * 8);

    __syncthreads();

    floatx4 acc[6];
    const floatx4 z4 = {0.0f, 0.0f, 0.0f, 0.0f};
    for (int j = 0; j < 6; ++j) acc[j] = z4;

    for (int kt = 0; kt < 8; ++kt)
        for (int j = 0; j < 6; ++j) {
            half8 bf = *(const half8*)&Bs[j * 16 + col][kt * 32 + quad * 8];
            acc[j] = __builtin_amdgcn_mfma_f32_16x16x32_f16(af[kt], bf, acc[j], 0, 0, 0);
        }

    // epilogue: acc[p]=r, acc[2+p]=z, acc[4+p]=n for channel c0+p*16+col (same lane!)
    const float* xgt = xg + (size_t)t * (BB * GG);
    const float* hprev = h32 + (size_t)(t & 1) * (BB * HH);
    float* hnew = h32 + (size_t)((t + 1) & 1) * (BB * HH);
    f16* hsout = hs_ext + (size_t)(t + 1) * (BB * HH);

    for (int p = 0; p < 2; ++p) {
        int c = c0 + p * 16 + col;
        float br = bhh[c], bz = bhh[256 + c], bn = bhh[512 + c];
        for (int r2 = 0; r2 < 4; ++r2) {
            int b = wave * 16 + quad * 4 + r2;
            float xr = xgt[(size_t)b * GG + c];
            float xz = xgt[(size_t)b * GG + 256 + c];
            float xn = xgt[(size_t)b * GG + 512 + c];
            float rv = sigm(xr + acc[p][r2] + br);
            float zv = sigm(xz + acc[2 + p][r2] + bz);
            float nv = tanh_(xn + rv * (acc[4 + p][r2] + bn));
            float hp = hprev[b * HH + c];
            float h = (1.0f - zv) * nv + zv * hp;
            hnew[b * HH + c] = h;
            hsout[b * HH + c] = (f16)h;
        }
    }
}

// ---------------- fused head: relu(h@fc1^T+b1) @ fco^T + b2 ----------------
__global__ __launch_bounds__(128) void fc_head(const float* __restrict__ h,
                                               const float* __restrict__ w1,
                                               const float* __restrict__ b1,
                                               const float* __restrict__ w2,
                                               const float* __restrict__ b2,
                                               float* __restrict__ out) {
    int b = blockIdx.x, f = threadIdx.x;
    const float* hb = h + b * HH;
    const float* wr = w1 + (size_t)f * HH;
    float a = b1[f];
    for (int c = 0; c < HH; c += 4) {
        float4 wv = *(const float4*)(wr + c);
        float4 hv = *(const float4*)(hb + c);
        a += wv.x * hv.x + wv.y * hv.y + wv.z * hv.z + wv.w * hv.w;
    }
    float z = fmaxf(a, 0.0f) * w2[f];
    for (int off = 32; off; off >>= 1) z += __shfl_down(z, off, 64);
    __shared__ float red[2];
    if ((f & 63) == 0) red[f >> 6] = z;
    __syncthreads();
    if (f == 0) out[b] = red[0] + red[1] + b2[0];
}

extern "C" void kernel_launch(void* const* d_in, const int* in_sizes, int n_in,
                              void* d_out, int out_size, void* d_ws, size_t ws_size,
                              hipStream_t stream) {
    const float* x = (const float*)d_in[0];
    const float* wih[3] = {(const float*)d_in[1], (const float*)d_in[5], (const float*)d_in[9]};
    const float* whh[3] = {(const float*)d_in[2], (const float*)d_in[6], (const float*)d_in[10]};
    const float* bih[3] = {(const float*)d_in[3], (const float*)d_in[7], (const float*)d_in[11]};
    const float* bhh[3] = {(const float*)d_in[4], (const float*)d_in[8], (const float*)d_in[12]};
    const float* fc1w = (const float*)d_in[13];
    const float* fc1b = (const float*)d_in[14];
    const float* fcow = (const float*)d_in[15];
    const float* fcob = (const float*)d_in[16];

    char* p = (char*)d_ws;
    auto alloc = [&](size_t bytes) {
        void* r = (void*)p;
        p += (bytes + 255) & ~(size_t)255;
        return r;
    };
    float* xg = (float*)alloc((size_t)TT * BB * GG * 4);            // 100.7 MB, reused per layer
    f16* wih0h = (f16*)alloc((size_t)GG * II * 2);
    f16* wih1h = (f16*)alloc((size_t)GG * HH * 2);
    f16* wih2h = (f16*)alloc((size_t)GG * HH * 2);
    f16* whhh[3];
    for (int l = 0; l < 3; ++l) whhh[l] = (f16*)alloc((size_t)GG * HH * 2);
    f16* hs[3];
    for (int l = 0; l < 3; ++l) hs[l] = (f16*)alloc((size_t)(TT + 1) * BB * HH * 2);
    float* h32 = (float*)alloc((size_t)2 * BB * HH * 4);

    // weight converts
    {
        int n0 = GG * II;
        cvt<<<(n0 / 4 + 255) / 256, 256, 0, stream>>>(wih[0], wih0h, n0);
        int n1 = GG * HH;
        cvt<<<(n1 / 4 + 255) / 256, 256, 0, stream>>>(wih[1], wih1h, n1);
        cvt<<<(n1 / 4 + 255) / 256, 256, 0, stream>>>(wih[2], wih2h, n1);
        for (int l = 0; l < 3; ++l)
            cvt<<<(n1 / 4 + 255) / 256, 256, 0, stream>>>(whh[l], whhh[l], n1);
    }
    // zero hs slot 0 (h(-1) = 0) for all layers: 64*256 f16 = 32768 B = 2048 uint4
    for (int l = 0; l < 3; ++l) zero16<<<8, 256, 0, stream>>>((uint4*)hs[l], 2048);

    f16* wihh_l[3] = {wih0h, wih1h, wih2h};
    for (int l = 0; l < 3; ++l) {
        if (l == 0)
            proj<II, true><<<dim3(6, 256), 256, 0, stream>>>((const void*)x, wih0h, bih[0], xg);
        else
            proj<HH, false><<<dim3(6, 256), 256, 0, stream>>>((const void*)(hs[l - 1] + BB * HH),
                                                              wihh_l[l], bih[l], xg);
        // zero h32 slot 0: 64*256 f32 = 65536 B = 4096 uint4
        zero16<<<16, 256, 0, stream>>>((uint4*)h32, 4096);
        for (int t = 0; t < TT; ++t)
            gru_step<<<8, 256, 0, stream>>>(xg, whhh[l], bhh[l], hs[l], h32, t);
    }
    // final h of layer 2 is h32 slot ((511+1)&1) == 0
    fc_head<<<64, 128, 0, stream>>>(h32, fc1w, fc1b, fcow, fcob, (float*)d_out);
}

// Round 2
// 7362.468 us; speedup vs baseline: 1.5498x; 1.5498x over previous
//
#include <hip/hip_runtime.h>

typedef _Float16 f16;
typedef _Float16 half8 __attribute__((ext_vector_type(8)));
typedef _Float16 half4_t __attribute__((ext_vector_type(4)));
typedef float floatx4 __attribute__((ext_vector_type(4)));

#define BB 64
#define TT 512
#define II 2048
#define HH 256
#define GG 768  // 3*H

__device__ inline float sigm(float x) { return 1.0f / (1.0f + __expf(-x)); }
__device__ inline float tanh_(float x) { float t = __expf(2.0f * x); return 1.0f - 2.0f / (t + 1.0f); }

// ---------------- zero fill (16B granules) ----------------
__global__ void zero16(uint4* p, int n16) {
    int i = blockIdx.x * blockDim.x + threadIdx.x;
    if (i < n16) p[i] = make_uint4(0u, 0u, 0u, 0u);
}

// ---------------- fp32 -> fp16 convert ----------------
__global__ void cvt(const float* __restrict__ s, f16* __restrict__ d, int n) {
    int i = (blockIdx.x * blockDim.x + threadIdx.x) * 4;
    if (i + 3 < n) {
        float4 v = *(const float4*)(s + i);
        d[i + 0] = (f16)v.x; d[i + 1] = (f16)v.y; d[i + 2] = (f16)v.z; d[i + 3] = (f16)v.w;
    } else {
        for (; i < n; ++i) d[i] = (f16)s[i];
    }
}

// ---------------- input projection GEMM ----------------
// out[M=32768][768] = A[M][K] @ W[768][K]^T + bias[768]
// REMAP: A is x (fp32, [b][t][I] layout, row r=(t,b) -> x[b][t][:]), convert in-tile.
// else:  A is fp16 rows contiguous with stride K.
template <int K, bool REMAP>
__global__ __launch_bounds__(256) void proj(const void* __restrict__ Avoid,
                                            const f16* __restrict__ W,
                                            const float* __restrict__ bias,
                                            float* __restrict__ out) {
    __shared__ f16 As[128][40];  // 128 x 32 (+8 pad): 16B-aligned rows
    __shared__ f16 Bs[128][40];
    const int tid = threadIdx.x;
    const int wave = tid >> 6, lane = tid & 63, quad = lane >> 4, col = lane & 15;
    const int nt = blockIdx.x, mt = blockIdx.y;
    const int wm = wave >> 1, wn = wave & 1;

    floatx4 acc[4][4];
    const floatx4 z4 = {0.0f, 0.0f, 0.0f, 0.0f};
    for (int a = 0; a < 4; ++a)
        for (int b = 0; b < 4; ++b) acc[a][b] = z4;

    const int srow = tid >> 1;   // staging: 2 threads per row
    const int kh = tid & 1;      // k-half (16 elements each)

    for (int kt = 0; kt < K / 32; ++kt) {
        const int k0 = kt * 32;
        __syncthreads();
        if (REMAP) {
            const float* x = (const float*)Avoid;
            int r = mt * 128 + srow;
            int t = r >> 6, b = r & 63;
            const float* src = x + ((size_t)b * TT + t) * (size_t)II + k0 + kh * 16;
            for (int j = 0; j < 4; ++j) {
                float4 v = *(const float4*)(src + j * 4);
                half4_t h;
                h.x = (f16)v.x; h.y = (f16)v.y; h.z = (f16)v.z; h.w = (f16)v.w;
                *(half4_t*)&As[srow][kh * 16 + j * 4] = h;
            }
        } else {
            const f16* Af = (const f16*)Avoid;
            int r = mt * 128 + srow;
            const f16* src = Af + (size_t)r * K + k0 + kh * 16;
            uint4* dst = (uint4*)&As[srow][kh * 16];
            dst[0] = *(const uint4*)(src);
            dst[1] = *(const uint4*)(src + 8);
        }
        {
            const f16* src = W + (size_t)(nt * 128 + srow) * K + k0 + kh * 16;
            uint4* dst = (uint4*)&Bs[srow][kh * 16];
            dst[0] = *(const uint4*)(src);
            dst[1] = *(const uint4*)(src + 8);
        }
        __syncthreads();

        half8 af[4], bf[4];
        for (int mi = 0; mi < 4; ++mi) af[mi] = *(const half8*)&As[wm * 64 + mi * 16 + col][quad * 8];
        for (int ni = 0; ni < 4; ++ni) bf[ni] = *(const half8*)&Bs[wn * 64 + ni * 16 + col][quad * 8];
        for (int mi = 0; mi < 4; ++mi)
            for (int ni = 0; ni < 4; ++ni)
                acc[mi][ni] = __builtin_amdgcn_mfma_f32_16x16x32_f16(af[mi], bf[ni], acc[mi][ni], 0, 0, 0);
    }

    for (int mi = 0; mi < 4; ++mi)
        for (int ni = 0; ni < 4; ++ni)
            for (int r2 = 0; r2 < 4; ++r2) {
                int m = mt * 128 + wm * 64 + mi * 16 + quad * 4 + r2;
                int n = nt * 128 + wn * 64 + ni * 16 + col;
                out[(size_t)m * GG + n] = acc[mi][ni][r2] + bias[n];
            }
}

// ---------------- device-scope grid barrier (monotonic counter) ----------------
__device__ inline void grid_bar(unsigned* cnt, unsigned target) {
    __syncthreads();  // all waves' prior stores drained (s_barrier implies vmcnt wait)
    if (threadIdx.x == 0) {
        __hip_atomic_fetch_add(cnt, 1u, __ATOMIC_RELEASE, __HIP_MEMORY_SCOPE_AGENT);
        while (__hip_atomic_load(cnt, __ATOMIC_ACQUIRE, __HIP_MEMORY_SCOPE_AGENT) < target)
            __builtin_amdgcn_s_sleep(2);
    }
    __syncthreads();
}

// ---------------- persistent GRU layer: 8 WGs loop over all 512 steps ----------------
// WG owns 32 channels; w_hh fragments register-resident (48 x half8 = 192 VGPR).
// h fp32 state register-resident (same lane produces & consumes). Only cross-WG
// traffic: fp16 h all-to-all via hs_ext + streamed xg reads.
__global__ __launch_bounds__(256, 1) void gru_layer(const float* __restrict__ xg,
                                                    const f16* __restrict__ whh,
                                                    const float* __restrict__ bhh,
                                                    f16* __restrict__ hs_ext,
                                                    float* __restrict__ hfinal,
                                                    unsigned* __restrict__ bar) {
    const int tid = threadIdx.x, wave = tid >> 6, lane = tid & 63, quad = lane >> 4, col = lane & 15;
    const int c0 = blockIdx.x * 32;

    // B fragments: rows [0,32)=r, [32,64)=z, [64,96)=n for channels c0..c0+31
    half8 bfr[6][8];
#pragma unroll
    for (int j = 0; j < 6; ++j) {
        int rr = j * 16 + col;
        int g = rr >> 5, cloc = rr & 31;
        const f16* wrow = whh + ((size_t)(g * 256 + c0 + cloc)) * 256;
#pragma unroll
        for (int kt = 0; kt < 8; ++kt)
            bfr[j][kt] = *(const half8*)(wrow + kt * 32 + quad * 8);
    }
    float br[2], bz[2], bn[2];
#pragma unroll
    for (int p = 0; p < 2; ++p) {
        int c = c0 + p * 16 + col;
        br[p] = bhh[c]; bz[p] = bhh[256 + c]; bn[p] = bhh[512 + c];
    }
    float hreg[2][4];
#pragma unroll
    for (int p = 0; p < 2; ++p)
#pragma unroll
        for (int r2 = 0; r2 < 4; ++r2) hreg[p][r2] = 0.0f;

    const int m = wave * 16 + col;
    const floatx4 z4 = {0.0f, 0.0f, 0.0f, 0.0f};

    for (int t = 0; t < TT; ++t) {
        // A fragments: h(t-1) fp16, written by all WGs last step (slot 0 pre-zeroed)
        const f16* hA = hs_ext + (size_t)t * (BB * HH);
        half8 af[8];
#pragma unroll
        for (int kt = 0; kt < 8; ++kt)
            af[kt] = *(const half8*)(hA + (size_t)m * 256 + kt * 32 + quad * 8);

        // prefetch xg for this step (independent of h -> overlaps MFMA)
        const float* xgt = xg + (size_t)t * (BB * GG);
        float xr[2][4], xz[2][4], xn[2][4];
#pragma unroll
        for (int p = 0; p < 2; ++p) {
            int c = c0 + p * 16 + col;
#pragma unroll
            for (int r2 = 0; r2 < 4; ++r2) {
                int b = wave * 16 + quad * 4 + r2;
                const float* q = xgt + (size_t)b * GG + c;
                xr[p][r2] = q[0]; xz[p][r2] = q[256]; xn[p][r2] = q[512];
            }
        }

        floatx4 acc[6];
#pragma unroll
        for (int j = 0; j < 6; ++j) acc[j] = z4;
#pragma unroll
        for (int kt = 0; kt < 8; ++kt)
#pragma unroll
            for (int j = 0; j < 6; ++j)
                acc[j] = __builtin_amdgcn_mfma_f32_16x16x32_f16(af[kt], bfr[j][kt], acc[j], 0, 0, 0);

        f16* hsout = hs_ext + (size_t)(t + 1) * (BB * HH);
#pragma unroll
        for (int p = 0; p < 2; ++p) {
            int c = c0 + p * 16 + col;
#pragma unroll
            for (int r2 = 0; r2 < 4; ++r2) {
                int b = wave * 16 + quad * 4 + r2;
                float rv = sigm(xr[p][r2] + acc[p][r2] + br[p]);
                float zv = sigm(xz[p][r2] + acc[2 + p][r2] + bz[p]);
                float nv = tanh_(xn[p][r2] + rv * (acc[4 + p][r2] + bn[p]));
                float h = (1.0f - zv) * nv + zv * hreg[p][r2];
                hreg[p][r2] = h;
                hsout[(size_t)b * HH + c] = (f16)h;
                if (t == TT - 1) hfinal[(size_t)b * HH + c] = h;
            }
        }

        grid_bar(bar, 8u * (unsigned)(t + 1));
    }
}

// ---------------- fused head: relu(h@fc1^T+b1) @ fco^T + b2 ----------------
__global__ __launch_bounds__(128) void fc_head(const float* __restrict__ h,
                                               const float* __restrict__ w1,
                                               const float* __restrict__ b1,
                                               const float* __restrict__ w2,
                                               const float* __restrict__ b2,
                                               float* __restrict__ out) {
    int b = blockIdx.x, f = threadIdx.x;
    const float* hb = h + b * HH;
    const float* wr = w1 + (size_t)f * HH;
    float a = b1[f];
    for (int c = 0; c < HH; c += 4) {
        float4 wv = *(const float4*)(wr + c);
        float4 hv = *(const float4*)(hb + c);
        a += wv.x * hv.x + wv.y * hv.y + wv.z * hv.z + wv.w * hv.w;
    }
    float z = fmaxf(a, 0.0f) * w2[f];
    for (int off = 32; off; off >>= 1) z += __shfl_down(z, off, 64);
    __shared__ float red[2];
    if ((f & 63) == 0) red[f >> 6] = z;
    __syncthreads();
    if (f == 0) out[b] = red[0] + red[1] + b2[0];
}

extern "C" void kernel_launch(void* const* d_in, const int* in_sizes, int n_in,
                              void* d_out, int out_size, void* d_ws, size_t ws_size,
                              hipStream_t stream) {
    const float* x = (const float*)d_in[0];
    const float* wih[3] = {(const float*)d_in[1], (const float*)d_in[5], (const float*)d_in[9]};
    const float* whh[3] = {(const float*)d_in[2], (const float*)d_in[6], (const float*)d_in[10]};
    const float* bih[3] = {(const float*)d_in[3], (const float*)d_in[7], (const float*)d_in[11]};
    const float* bhh[3] = {(const float*)d_in[4], (const float*)d_in[8], (const float*)d_in[12]};
    const float* fc1w = (const float*)d_in[13];
    const float* fc1b = (const float*)d_in[14];
    const float* fcow = (const float*)d_in[15];
    const float* fcob = (const float*)d_in[16];

    char* p = (char*)d_ws;
    auto alloc = [&](size_t bytes) {
        void* r = (void*)p;
        p += (bytes + 255) & ~(size_t)255;
        return r;
    };
    float* xg = (float*)alloc((size_t)TT * BB * GG * 4);  // 100.7 MB, reused per layer
    f16* wih0h = (f16*)alloc((size_t)GG * II * 2);
    f16* wih1h = (f16*)alloc((size_t)GG * HH * 2);
    f16* wih2h = (f16*)alloc((size_t)GG * HH * 2);
    f16* whhh[3];
    for (int l = 0; l < 3; ++l) whhh[l] = (f16*)alloc((size_t)GG * HH * 2);
    f16* hs[3];
    for (int l = 0; l < 3; ++l) hs[l] = (f16*)alloc((size_t)(TT + 1) * BB * HH * 2);
    float* hfinal = (float*)alloc((size_t)BB * HH * 4);
    unsigned* bars = (unsigned*)alloc(256);  // 3 barrier counters

    // weight converts
    {
        int n0 = GG * II;
        cvt<<<(n0 / 4 + 255) / 256, 256, 0, stream>>>(wih[0], wih0h, n0);
        int n1 = GG * HH;
        cvt<<<(n1 / 4 + 255) / 256, 256, 0, stream>>>(wih[1], wih1h, n1);
        cvt<<<(n1 / 4 + 255) / 256, 256, 0, stream>>>(wih[2], wih2h, n1);
        for (int l = 0; l < 3; ++l)
            cvt<<<(n1 / 4 + 255) / 256, 256, 0, stream>>>(whh[l], whhh[l], n1);
    }
    // zero hs slot 0 (h(-1)=0) for all layers: 64*256 f16 = 2048 uint4
    for (int l = 0; l < 3; ++l) zero16<<<8, 256, 0, stream>>>((uint4*)hs[l], 2048);
    // zero barrier counters (ws is poisoned 0xAA)
    zero16<<<1, 64, 0, stream>>>((uint4*)bars, 16);

    f16* wihh_l[3] = {wih0h, wih1h, wih2h};
    for (int l = 0; l < 3; ++l) {
        if (l == 0)
            proj<II, true><<<dim3(6, 256), 256, 0, stream>>>((const void*)x, wih0h, bih[0], xg);
        else
            proj<HH, false><<<dim3(6, 256), 256, 0, stream>>>((const void*)(hs[l - 1] + BB * HH),
                                                              wihh_l[l], bih[l], xg);
        gru_layer<<<8, 256, 0, stream>>>(xg, whhh[l], bhh[l], hs[l], hfinal, bars + l * 16);
    }
    fc_head<<<64, 128, 0, stream>>>(hfinal, fc1w, fc1b, fcow, fcob, (float*)d_out);
}